// Round 1
// baseline (319.961 us; speedup 1.0000x reference)
//
#include <hip/hip_runtime.h>

typedef unsigned long long ull;

// 8 batches x 4096 seq = 32768 positions; 16 slots x 80 floats = 1280 out/pos.
// One wave (64 lanes) per position: hash on lanes (slot = lane&15), then copy
// 320 float4 per position (5 per lane, coalesced).
__global__ __launch_bounds__(256, 4)
void engram_kernel(const int* __restrict__ ids,
                   const int* __restrict__ seeds,
                   const float* __restrict__ t0,  const float* __restrict__ t1,
                   const float* __restrict__ t2,  const float* __restrict__ t3,
                   const float* __restrict__ t4,  const float* __restrict__ t5,
                   const float* __restrict__ t6,  const float* __restrict__ t7,
                   const float* __restrict__ t8,  const float* __restrict__ t9,
                   const float* __restrict__ t10, const float* __restrict__ t11,
                   const float* __restrict__ t12, const float* __restrict__ t13,
                   const float* __restrict__ t14, const float* __restrict__ t15,
                   float* __restrict__ out)
{
    __shared__ const float* tab[16];
    __shared__ int szs[16];
    if (threadIdx.x == 0) {
        tab[0]=t0;  tab[1]=t1;  tab[2]=t2;  tab[3]=t3;
        tab[4]=t4;  tab[5]=t5;  tab[6]=t6;  tab[7]=t7;
        tab[8]=t8;  tab[9]=t9;  tab[10]=t10; tab[11]=t11;
        tab[12]=t12; tab[13]=t13; tab[14]=t14; tab[15]=t15;
        szs[0]=6619;  szs[1]=6637;  szs[2]=6653;  szs[3]=6659;
        szs[4]=6661;  szs[5]=6673;  szs[6]=6679;  szs[7]=6689;
        szs[8]=65521; szs[9]=65537; szs[10]=65539; szs[11]=65543;
        szs[12]=65551; szs[13]=65557; szs[14]=65563; szs[15]=65579;
    }
    __syncthreads();

    const int wave = threadIdx.x >> 6;
    const int lane = threadIdx.x & 63;
    const int pos  = blockIdx.x * 4 + wave;      // grid = 8192 -> pos < 32768
    const int b = pos >> 12;
    const int s = pos & 4095;

    const int* row = ids + (b << 12);
    const int id0  = row[s];
    const int idm1 = (s >= 1) ? row[s - 1] : 0;  // left zero-pad per _ngrams
    const int idm2 = (s >= 2) ? row[s - 2] : 0;

    // hash for slot = lane&15 (slots 0..7: bigram heads, 8..15: trigram heads)
    const int slot = lane & 15;
    const int head = slot & 7;
    const ull sa = (ull)(unsigned)seeds[head];
    const ull sb = (ull)(unsigned)seeds[8 + head];
    ull h;
    if (slot < 8) {
        // ng = [ids[s-1], ids[s]] . seeds rows 0,1
        h = ((ull)(unsigned)idm1 * sa) ^ ((ull)(unsigned)id0 * sb);
    } else {
        // ng = [ids[s-2], ids[s-1], ids[s]] . seeds rows 0,1,2
        const ull sc = (ull)(unsigned)seeds[16 + head];
        h = ((ull)(unsigned)idm2 * sa) ^ ((ull)(unsigned)idm1 * sb)
            ^ ((ull)(unsigned)id0 * sc);
    }
    // products < 2^47 each, xor stays non-negative -> unsigned mod == jnp floored mod
    const unsigned sz  = (unsigned)szs[slot];
    const unsigned idx = (unsigned)(h % (ull)sz);

    // copy: 320 float4 per position; each lane does g = lane + 64*j
    float4* dst = (float4*)out + (size_t)pos * 320;
    #pragma unroll
    for (int j = 0; j < 5; ++j) {
        const int g  = lane + (j << 6);
        const int gs = g / 20;             // which slot this float4 belongs to
        const int off = g - gs * 20;       // float4 offset within the 80-float row
        const unsigned ridx = (unsigned)__shfl((int)idx, gs, 64);
        const float4* src = (const float4*)tab[gs] + (size_t)ridx * 20 + off;
        dst[g] = *src;
    }
}

extern "C" void kernel_launch(void* const* d_in, const int* in_sizes, int n_in,
                              void* d_out, int out_size, void* d_ws, size_t ws_size,
                              hipStream_t stream) {
    const int* ids   = (const int*)d_in[0];
    const int* seeds = (const int*)d_in[1];
    const float* t[16];
    for (int i = 0; i < 16; ++i) t[i] = (const float*)d_in[2 + i];

    engram_kernel<<<dim3(8192), dim3(256), 0, stream>>>(
        ids, seeds,
        t[0], t[1], t[2], t[3], t[4], t[5], t[6], t[7],
        t[8], t[9], t[10], t[11], t[12], t[13], t[14], t[15],
        (float*)d_out);
}